// Round 4
// baseline (576.279 us; speedup 1.0000x reference)
//
#include <hip/hip_runtime.h>
#include <hip/hip_bf16.h>
#include <stdint.h>

// EmotionTriadFusion on MI355X — Round 9: algebraic K-fold for G5 + co-scheduled
// independent GEMMs. B=16384, F=1024, E=28, A=2, T=128, H=4, HD=32.
//
// R8 (569us): launch fusion 19->9 gave -23us (~2.3us/launch). Three GEMM
// schedules all pin at ~29% MfmaUtil -> stop schedule tuning; attack algebra:
//   gate_h = gelu([ff|ctx]@Wg1 + bg1), ctx = apre@WOCT^T + BOC
//   => gate_h = gelu(ff@Wg1top + apre@WFOLD^T + BG1F)
//   WFOLD[f][d] = sum_c Wg1[1024+c][f] * WOC[d][c],  WOC = Wo@Wc (bf16 folds)
//   BG1F[f] = bg1[f] + sum_c BOC[c]*Wg1[1024+c][f]
// G5 K: 2048 -> 1152 (-44% FLOPs). G5 no longer needs CTX -> G5||G3 merge in
// one 512-block dispatch; G6||G4 likewise (GATEH moved to out_refined upper
// half to kill the out_summary alias). Launches 9 -> 7.
//
// Launches:
//  1 preamble : ffb+tokens (16384) | transposes (3600) | prep scatter (710)
//  2 folds_a  : WQQT, WOCT, WOC (gemm128 x24) + BG1F (4)
//  3 g12      : G2 kvh (768) + G1 qh (128) + WFOLD fold (8)
//  4 attn     -> attw (d_out) + APRE (ws)
//  5 big5     : G5 gh=gelu(FFB@Wg1top+APRE@WFOLD+BG1F) K=1152 (256 blk)
//             | G3 ctx=APRE@WocT+BOC K=128 (256 blk)      [independent]
//  6 big6     : G6 pre=FFB+sigmoid(gh@Wg2T+bg2)*ctx (256) | G4 summary (256)
//  7 ln       : LayerNorm(1024) PRE bf16 -> refined fp32
//
// Scratch in d_out: out_refined[0..32M)=CTX bf16, [32M..64M)=GATEH bf16 (both
// dead before ln writes fp32). out_summary[0..25M)=KVH (dead after attn),
// [32M..35M)=WOC/WFOLD/BG1F (dead before G4 writes fp32 summary).

using bf16 = __hip_bfloat16;
typedef __bf16 bf16x8 __attribute__((ext_vector_type(8)));
typedef float f32x4 __attribute__((ext_vector_type(4)));

__device__ __forceinline__ float b2f(bf16 x) { return __bfloat162float(x); }
__device__ __forceinline__ bf16 f2b(float x) { return __float2bfloat16(x); }

__device__ __forceinline__ float fast_tanh(float y) {
  float z = fabsf(y);
  float t = __expf(-2.f * z);
  float r = (1.f - t) / (1.f + t);
  return copysignf(r, y);
}
__device__ __forceinline__ float gelu_f(float x) {
  return 0.5f * x * (1.f + fast_tanh(0.7978845608028654f * (x + 0.044715f * x * x * x)));
}
__device__ __forceinline__ float sigmoid_f(float v) {
  return 1.f / (1.f + __expf(-v));
}

__device__ __forceinline__ void async_ld16(const void* g, void* l) {
  using GP = const __attribute__((address_space(1))) uint32_t*;
  using LP = __attribute__((address_space(3))) uint32_t*;
  __builtin_amdgcn_global_load_lds((GP)g, (LP)l, 16, 0, 0);
}

// ---------------------------------------------------------------------------
// gemm128 device body: tile MTx128, BK=64, 4 waves 2x2, wave (MT/2)x64.
// ---------------------------------------------------------------------------
template <int EPI, typename OutT, int MT>
__device__ __forceinline__ void gemm128_dev(
    int bx, int by,
    const bf16* A0, const bf16* A1, int ksplit, int lda0, int lda1,
    const bf16* __restrict__ BT, int K,
    const float* __restrict__ bias,
    OutT* out, int ldo,
    const bf16* ffp, const bf16* ctxp, int ldfc)
{
  constexpr int MIC = MT / 32;
  __shared__ uint16_t smA[MT * 64];
  __shared__ uint16_t smB[128 * 64];
  const int tid = threadIdx.x;
  const int w = tid >> 6;
  const int l = tid & 63;
  const int m0 = bx * MT;
  const int n0 = by * 128;
  const int wr = w >> 1, wc = w & 1;
  const int lrow = l & 15, lquad = l >> 4;
  const int rb = w * 8 + (l >> 3);
  const int cpos = l & 7;

  const f32x4 vzero = {0.f, 0.f, 0.f, 0.f};
  f32x4 acc[MIC][4];
#pragma unroll
  for (int i = 0; i < MIC; i++)
#pragma unroll
    for (int j = 0; j < 4; j++) acc[i][j] = vzero;

  for (int k0 = 0; k0 < K; k0 += 64) {
    __syncthreads();
#pragma unroll
    for (int i = 0; i < MIC; i++) {
      int row = i * 32 + rb;
      int cg = cpos ^ (row & 7);
      int kcol = k0 + cg * 8;
      const bf16* gp = (kcol < ksplit)
                           ? (A0 + (size_t)(m0 + row) * lda0 + kcol)
                           : (A1 + (size_t)(m0 + row) * lda1 + (kcol - ksplit));
      async_ld16(gp, &smA[(i * 32 + w * 8) * 64]);
    }
#pragma unroll
    for (int i = 0; i < 4; i++) {
      int row = i * 32 + rb;
      int cg = cpos ^ (row & 7);
      const bf16* gq = BT + (size_t)(n0 + row) * K + k0 + cg * 8;
      async_ld16(gq, &smB[(i * 32 + w * 8) * 64]);
    }
    __syncthreads();
#pragma unroll
    for (int kk = 0; kk < 2; kk++) {
      bf16x8 af[MIC], bfr[4];
      const int cc = kk * 4 + lquad;
#pragma unroll
      for (int mi = 0; mi < MIC; mi++) {
        int r = wr * (MT / 2) + mi * 16 + lrow;
        af[mi] = *(const bf16x8*)&smA[r * 64 + ((cc ^ (r & 7)) << 3)];
      }
#pragma unroll
      for (int ni = 0; ni < 4; ni++) {
        int r = wc * 64 + ni * 16 + lrow;
        bfr[ni] = *(const bf16x8*)&smB[r * 64 + ((cc ^ (r & 7)) << 3)];
      }
#pragma unroll
      for (int mi = 0; mi < MIC; mi++)
#pragma unroll
        for (int ni = 0; ni < 4; ni++)
          acc[mi][ni] =
              __builtin_amdgcn_mfma_f32_16x16x32_bf16(af[mi], bfr[ni], acc[mi][ni], 0, 0, 0);
    }
  }

  // epilogue: C/D layout col=lane&15, row=(lane>>4)*4+reg
#pragma unroll
  for (int mi = 0; mi < MIC; mi++) {
#pragma unroll
    for (int ni = 0; ni < 4; ni++) {
#pragma unroll
      for (int r = 0; r < 4; r++) {
        int row = m0 + wr * (MT / 2) + mi * 16 + lquad * 4 + r;
        int col = n0 + wc * 64 + ni * 16 + lrow;
        float v = acc[mi][ni][r] + (bias ? bias[col] : 0.f);
        if (EPI == 1) v = gelu_f(v);
        if (EPI == 2) {
          float gate = sigmoid_f(v);
          size_t fo = (size_t)row * ldfc + col;
          v = b2f(ffp[fo]) + gate * b2f(ctxp[fo]);
        }
        if constexpr (__is_same(OutT, float))
          out[(size_t)row * ldo + col] = v;
        else
          out[(size_t)row * ldo + col] = f2b(v);
      }
    }
  }
}

// ---------------------------------------------------------------------------
// gemm256 device body (R6 schedule — best measured): 256x256 tile, BK=64,
// 8 waves (2Mx4N), wave 128x64, 2x64KB LDS dbuf via passed smem (so merged
// kernels with two instantiations share one 128KB block), distance-2
// prefetch, counted vmcnt(8), raw s_barrier, setprio around MFMA clusters.
// A and B both support a K-split (two source arrays with own strides).
// ---------------------------------------------------------------------------
template <int EPI, typename OutT>
__device__ __forceinline__ void gemm256_dev(
    uint16_t* __restrict__ smem, int bx, int by,
    const bf16* A0, const bf16* A1, int ksplit, int lda0, int lda1,
    const bf16* B0, const bf16* B1, int bsplit, int ldb0, int ldb1,
    int K,
    const float* __restrict__ bias,
    OutT* out, int ldo,
    const bf16* ffp, const bf16* ctxp, int ldfc)
{
  const int tid = threadIdx.x;
  const int w = tid >> 6;       // wave 0..7
  const int l = tid & 63;
  const int m0 = bx * 256;
  const int n0 = by * 256;
  const int wr = w >> 2;        // M-half 0..1
  const int wc = w & 3;         // N-quarter 0..3
  const int lrow = l & 15, lquad = l >> 4;
  const int rb = tid >> 3;      // staging row within 64-row group
  const int cpos = tid & 7;     // staging 16B-chunk position
  const int NT = K >> 6;

  const f32x4 vzero = {0.f, 0.f, 0.f, 0.f};
  f32x4 acc[8][4];
#pragma unroll
  for (int mi = 0; mi < 8; mi++)
#pragma unroll
    for (int ni = 0; ni < 4; ni++) acc[mi][ni] = vzero;

  auto stage = [&](int buf, int tt) {
    const int k0 = tt << 6;
    const bf16* Ab; int la, kc;
    if (k0 < ksplit) { Ab = A0; la = lda0; kc = k0; }
    else             { Ab = A1; la = lda1; kc = k0 - ksplit; }
    uint16_t* sA = smem + buf * 16384;
#pragma unroll
    for (int i = 0; i < 4; i++) {
      const int row = i * 64 + rb;
      const int cg = cpos ^ (row & 7);
      async_ld16(Ab + (size_t)(m0 + row) * la + kc + cg * 8,
                 &sA[(i * 64 + w * 8) * 64]);
    }
    const bf16* Bb; int lb, kb;
    if (k0 < bsplit) { Bb = B0; lb = ldb0; kb = k0; }
    else             { Bb = B1; lb = ldb1; kb = k0 - bsplit; }
    uint16_t* sB = smem + 32768 + buf * 16384;
#pragma unroll
    for (int i = 0; i < 4; i++) {
      const int row = i * 64 + rb;
      const int cg = cpos ^ (row & 7);
      async_ld16(Bb + (size_t)(n0 + row) * lb + kb + cg * 8,
                 &sB[(i * 64 + w * 8) * 64]);
    }
  };

  int cur = 0;

  auto readfrags = [&](int kk, bf16x8 (&af)[8], bf16x8 (&bfr)[4]) {
    const uint16_t* sA = smem + cur * 16384;
    const uint16_t* sB = smem + 32768 + cur * 16384;
    const int cc = kk * 4 + lquad;
#pragma unroll
    for (int mi = 0; mi < 8; mi++) {
      int r = wr * 128 + mi * 16 + lrow;
      af[mi] = *(const bf16x8*)&sA[r * 64 + ((cc ^ (r & 7)) << 3)];
    }
#pragma unroll
    for (int ni = 0; ni < 4; ni++) {
      int r = wc * 64 + ni * 16 + lrow;
      bfr[ni] = *(const bf16x8*)&sB[r * 64 + ((cc ^ (r & 7)) << 3)];
    }
  };
  auto domfma = [&](bf16x8 (&af)[8], bf16x8 (&bfr)[4]) {
#pragma unroll
    for (int mi = 0; mi < 8; mi++)
#pragma unroll
      for (int ni = 0; ni < 4; ni++)
        acc[mi][ni] =
            __builtin_amdgcn_mfma_f32_16x16x32_bf16(af[mi], bfr[ni], acc[mi][ni], 0, 0, 0);
  };

  // prologue: stage tiles 0,1; wait tile 0 (8 oldest loads), sync.
  stage(0, 0);
  stage(1, 1);
  asm volatile("s_waitcnt vmcnt(8)" ::: "memory");
  __builtin_amdgcn_s_barrier();
  __builtin_amdgcn_sched_barrier(0);

  for (int t = 0; t < NT; ++t) {
    bf16x8 af[8], bfr[4];
    readfrags(0, af, bfr);
    __builtin_amdgcn_s_setprio(1);
    domfma(af, bfr);
    __builtin_amdgcn_s_setprio(0);
    readfrags(1, af, bfr);
    asm volatile("s_waitcnt lgkmcnt(0)" ::: "memory");  // all buf[cur] reads done
    __builtin_amdgcn_s_barrier();                       // ...for every wave
    __builtin_amdgcn_sched_barrier(0);
    if (t + 2 < NT) stage(cur, t + 2);                  // safe: buf[cur] free
    __builtin_amdgcn_s_setprio(1);
    domfma(af, bfr);
    __builtin_amdgcn_s_setprio(0);
    if (t + 2 < NT) {
      asm volatile("s_waitcnt vmcnt(8)" ::: "memory");  // tile t+1 landed
    } else {
      asm volatile("s_waitcnt vmcnt(0)" ::: "memory");  // tail: drain
    }
    __builtin_amdgcn_s_barrier();
    __builtin_amdgcn_sched_barrier(0);
    cur ^= 1;
  }

  // epilogue: C/D layout col=lane&15, row=(lane>>4)*4+reg
#pragma unroll
  for (int mi = 0; mi < 8; mi++) {
#pragma unroll
    for (int ni = 0; ni < 4; ni++) {
#pragma unroll
      for (int r = 0; r < 4; r++) {
        int row = m0 + wr * 128 + mi * 16 + lquad * 4 + r;
        int col = n0 + wc * 64 + ni * 16 + lrow;
        float v = acc[mi][ni][r] + (bias ? bias[col] : 0.f);
        if (EPI == 1) v = gelu_f(v);
        if (EPI == 2) {
          float gate = sigmoid_f(v);
          size_t fo = (size_t)row * ldfc + col;
          v = b2f(ffp[fo]) + gate * b2f(ctxp[fo]);
        }
        if constexpr (__is_same(OutT, float))
          out[(size_t)row * ldo + col] = v;
        else
          out[(size_t)row * ldo + col] = f2b(v);
      }
    }
  }
}

// ---------------------------------------------------------------------------
// Launch 5: G5 (K=1152, folded) || G3 (K=128) — independent after the fold.
// ---------------------------------------------------------------------------
__launch_bounds__(512, 2)
__global__ void big5_k(const bf16* FFB, const bf16* APRE,
                       const bf16* WG1T, const bf16* WFOLD, const float* BG1F,
                       bf16* GATEH,
                       const bf16* WOCT, const float* BOC, bf16* CTX)
{
  __shared__ uint16_t smem[65536];  // 128 KiB shared by both branches
  int bid = blockIdx.x;
  if (bid < 256) {
    // G5: gate_h = gelu(FFB@Wg1top^T + APRE@WFOLD^T + BG1F)
    gemm256_dev<1, bf16>(smem, bid & 63, bid >> 6,
                         FFB, APRE, 1024, 1024, 128,
                         WG1T, WFOLD, 1024, 2048, 128,
                         1152, BG1F, GATEH, 1024, nullptr, nullptr, 0);
  } else {
    bid -= 256;
    // G3: ctx = APRE @ WocT + BOC
    gemm256_dev<0, bf16>(smem, bid & 63, bid >> 6,
                         APRE, APRE, 128, 128, 128,
                         WOCT, WOCT, 128, 128, 128,
                         128, BOC, CTX, 1024, nullptr, nullptr, 0);
  }
}

// ---------------------------------------------------------------------------
// Launch 6: G6 (gate epilogue) || G4 (summary) — independent (GATEH no longer
// aliases out_summary).
// ---------------------------------------------------------------------------
__launch_bounds__(512, 2)
__global__ void big6_k(const bf16* GATEH, const bf16* WG2T, const float* bg2,
                       bf16* PRE, const bf16* FFB, const bf16* CTX,
                       const bf16* TOK, const bf16* WST, const float* bs, float* SUMM)
{
  __shared__ uint16_t smem[65536];
  int bid = blockIdx.x;
  if (bid < 256) {
    // G6: pre = FFB + sigmoid(GATEH@Wg2T + bg2) * CTX   (PRE aliases FFB elem-wise)
    gemm256_dev<2, bf16>(smem, bid & 63, bid >> 6,
                         GATEH, GATEH, 1024, 1024, 1024,
                         WG2T, WG2T, 1024, 1024, 1024,
                         1024, bg2, PRE, 1024, FFB, CTX, 1024);
  } else {
    bid -= 256;
    // G4: summary = gelu(TOK @ WsT + bs)
    gemm256_dev<1, float>(smem, bid & 63, bid >> 6,
                          TOK, TOK, 384, 384, 384,
                          WST, WST, 384, 384, 384,
                          384, bs, SUMM, 1024, nullptr, nullptr, 0);
  }
}

// ---------------------------------------------------------------------------
// Launch 2: weight folds A — WQQT, WOCT, WOC (gemm128) + BG1F (serial dot).
// ---------------------------------------------------------------------------
__launch_bounds__(256)
__global__ void folds_a(const bf16* WQT, const bf16* WQINB, bf16* WQQT,
                        const bf16* WCT, const bf16* WOB, bf16* WOCT, bf16* WOC,
                        const float* __restrict__ Wg1, const float* __restrict__ BOC,
                        const float* __restrict__ bg1, float* BG1F)
{
  int bid = blockIdx.x;
  if (bid < 8) {
    // WQQT[t][f] = sum_u Wq[u][t]*Wq_in[f][u]  (M=128, N=1024, K=128)
    gemm128_dev<0, bf16, 128>(0, bid, WQT, WQT, 128, 128, 128, WQINB, 128,
                              nullptr, WQQT, 1024, nullptr, nullptr, 0);
  } else if (bid < 16) {
    // WOCT[f][d] = sum_t Wc[t][f]*Wo[d][t]     (M=1024, N=128, K=128)
    gemm128_dev<0, bf16, 128>(bid - 8, 0, WCT, WCT, 128, 128, 128, WOB, 128,
                              nullptr, WOCT, 128, nullptr, nullptr, 0);
  } else if (bid < 24) {
    // WOC[d][c] = sum_t Wo[d][t]*Wc[t][c]      (M=128, N=1024, K=128)
    gemm128_dev<0, bf16, 128>(0, bid - 16, WOB, WOB, 128, 128, 128, WCT, 128,
                              nullptr, WOC, 1024, nullptr, nullptr, 0);
  } else {
    // BG1F[f] = bg1[f] + sum_c BOC[c]*Wg1[1024+c][f]  (coalesced over f)
    int f = (bid - 24) * 256 + threadIdx.x;
    float s = bg1[f];
    for (int c = 0; c < 1024; c++) s += BOC[c] * Wg1[(size_t)(1024 + c) * 1024 + f];
    BG1F[f] = s;
  }
}

// ---------------------------------------------------------------------------
// Launch 3: G2 (768) + G1 (128) + WFOLD fold (8).
// ---------------------------------------------------------------------------
__launch_bounds__(256)
__global__ void g12_k(const bf16* FFB, const bf16* WQQT, const float* BQQ, bf16* QH,
                      const bf16* TOK, const bf16* WKVT, const float* BKV, bf16* KVH,
                      const bf16* WG1T, const bf16* WOC, bf16* WFOLD)
{
  int bid = blockIdx.x;
  if (bid < 768) {
    // G2: kvh = TOK @ [Wk|Wv]T  (M=49152, K=128, N=256)
    gemm128_dev<0, bf16, 128>(bid % 384, bid / 384, TOK, TOK, 128, 128, 128,
                              WKVT, 128, BKV, KVH, 256, nullptr, nullptr, 0);
  } else if (bid < 896) {
    // G1: qh = FFB @ WqqT + bqq  (M=16384, K=1024, N=128)
    gemm128_dev<0, bf16, 128>(bid - 768, 0, FFB, FFB, 1024, 1024, 1024,
                              WQQT, 1024, BQQ, QH, 128, nullptr, nullptr, 0);
  } else {
    // WFOLD[f][d] = sum_c Wg1T[f][1024+c] * WOC[d][c]  (M=1024, N=128, K=1024)
    gemm128_dev<0, bf16, 128>(bid - 896, 0, WG1T + 1024, WG1T + 1024, 2048, 2048, 2048,
                              WOC, 1024, nullptr, WFOLD, 128, nullptr, nullptr, 0);
  }
}

// ---------------------------------------------------------------------------
// emb28 with 256-thread blocks (writes guarded to t<128; syncs unconditional).
// ---------------------------------------------------------------------------
__device__ __forceinline__ void emb28_256(const float* __restrict__ logits,
                                          const float* __restrict__ g,
                                          const float* __restrict__ bb,
                                          const float* __restrict__ W,
                                          const float* __restrict__ wb,
                                          bf16* __restrict__ out, int t,
                                          float* sv, float* sp)
{
  if (t < 28) sv[t] = logits[t];
  __syncthreads();
  float mx = sv[0];
#pragma unroll
  for (int e = 1; e < 28; e++) mx = fmaxf(mx, sv[e]);
  if (t < 28) sp[t] = __expf(sv[t] - mx);
  __syncthreads();
  float sum = 0.f;
#pragma unroll
  for (int e = 0; e < 28; e++) sum += sp[e];
  float inv = 1.f / sum;
  float sp2 = 0.f;
#pragma unroll
  for (int e = 0; e < 28; e++) { float p = sp[e] * inv; sp2 += p * p; }
  const float mean = 1.f / 28.f;
  float var = sp2 * (1.f / 28.f) - mean * mean;
  float rstd = rsqrtf(var + 1e-5f);
  __syncthreads();
  if (t < 28) sp[t] = (sp[t] * inv - mean) * rstd * g[t] + bb[t];
  __syncthreads();
  if (t < 128) {
    float acc = wb[t];
#pragma unroll
    for (int e = 0; e < 28; e++) acc += sp[e] * W[e * 128 + t];
    out[t] = f2b(gelu_f(acc));
  }
  __syncthreads();
}

// ---------------------------------------------------------------------------
// Launch 1: preamble — grid-partitioned.
//  [0, 16384)          : ffb convert (row b) + tokens (row b), 256 thr
//  [16384, 19984)      : weight transposes (32x32 tiles via LDS 32x33)
//  [19984, 20694)      : prep scatter (WKVT/BKV/BQQ/BOC/WQINB/WOB)
// ---------------------------------------------------------------------------
__global__ void preamble(
    const float* __restrict__ ff, bf16* __restrict__ FFB,
    const float* __restrict__ exl, const float* __restrict__ iml, const float* __restrict__ affv,
    const float* __restrict__ geg, const float* __restrict__ geb,
    const float* __restrict__ Wex, const float* __restrict__ bex,
    const float* __restrict__ gig, const float* __restrict__ gib,
    const float* __restrict__ Wim, const float* __restrict__ bim,
    const float* __restrict__ gag, const float* __restrict__ gab,
    const float* __restrict__ Waf, const float* __restrict__ baf,
    bf16* __restrict__ TOK,
    const float* __restrict__ Wq, const float* __restrict__ Wc,
    const float* __restrict__ Ws, const float* __restrict__ Wg1,
    const float* __restrict__ Wg2,
    bf16* WQT, bf16* WCT, bf16* WST, bf16* WG1T, bf16* WG2T,
    const float* __restrict__ Wk, const float* __restrict__ bk,
    const float* __restrict__ Wv, const float* __restrict__ bv,
    const float* __restrict__ Wq_in, const float* __restrict__ bq_in,
    const float* __restrict__ bq, const float* __restrict__ Wo,
    const float* __restrict__ bo, const float* __restrict__ bc,
    bf16* WKVT, float* BKV, float* BQQ, float* BOC, bf16* WQINB, bf16* WOB)
{
  __shared__ float tile[32][33];
  __shared__ float sv[28], sp[28];
  int bid = blockIdx.x;
  const int t = threadIdx.x;

  if (bid < 16384) {
    // --- ffb convert: row bid (1024 floats, 4/thread) ---
    size_t i = (size_t)bid * 1024 + (size_t)t * 4;
    float4 v = *reinterpret_cast<const float4*>(ff + i);
    ushort4 o;
    o.x = __builtin_bit_cast(unsigned short, f2b(v.x));
    o.y = __builtin_bit_cast(unsigned short, f2b(v.y));
    o.z = __builtin_bit_cast(unsigned short, f2b(v.z));
    o.w = __builtin_bit_cast(unsigned short, f2b(v.w));
    *reinterpret_cast<ushort4*>(FFB + i) = o;
    // --- tokens: row bid ---
    bf16* trow = TOK + (size_t)bid * 384;
    emb28_256(exl + (size_t)bid * 28, geg, geb, Wex, bex, trow, t, sv, sp);
    emb28_256(iml + (size_t)bid * 28, gig, gib, Wim, bim, trow + 128, t, sv, sp);
    if (t < 128) {
      float a0 = affv[(size_t)bid * 2 + 0];
      float a1 = affv[(size_t)bid * 2 + 1];
      float m = 0.5f * (a0 + a1);
      float d0 = a0 - m, d1 = a1 - m;
      float var = 0.5f * (d0 * d0 + d1 * d1);
      float rstd = rsqrtf(var + 1e-5f);
      float l0 = d0 * rstd * gag[0] + gab[0];
      float l1 = d1 * rstd * gag[1] + gab[1];
      float acc = baf[t] + l0 * Waf[t] + l1 * Waf[128 + t];
      trow[256 + t] = f2b(gelu_f(acc));
    }
    return;
  }
  bid -= 16384;
  if (bid < 3600) {
    // --- transposes: out[c][r] = (bf16)in[r][c] ---
    const float* in; bf16* outp; int R, C, bx, by;
    if (bid < 16)                 { in = Wq;  outp = WQT;  R = 128;  C = 128;  bx = bid & 3;  by = bid >> 2; }
    else if ((bid -= 16) < 128)   { in = Wc;  outp = WCT;  R = 128;  C = 1024; bx = bid & 31; by = bid >> 5; }
    else if ((bid -= 128) < 384)  { in = Ws;  outp = WST;  R = 384;  C = 1024; bx = bid & 31; by = bid >> 5; }
    else if ((bid -= 384) < 2048) { in = Wg1; outp = WG1T; R = 2048; C = 1024; bx = bid & 31; by = bid >> 5; }
    else { bid -= 2048;             in = Wg2; outp = WG2T; R = 1024; C = 1024; bx = bid & 31; by = bid >> 5; }
    const int tx = t & 31, ty = t >> 5;  // ty in [0,8)
    const int c0 = bx * 32, r0 = by * 32;
#pragma unroll
    for (int i = 0; i < 4; i++) {
      int r = ty + i * 8;
      tile[r][tx] = in[(size_t)(r0 + r) * C + c0 + tx];
    }
    __syncthreads();
#pragma unroll
    for (int i = 0; i < 4; i++) {
      int c = ty + i * 8;
      outp[(size_t)(c0 + c) * R + r0 + tx] = f2b(tile[tx][c]);
    }
    return;
  }
  bid -= 3600;
  // --- prep scatter ---
  int idx = bid * 256 + t;
  if (idx < 32768) {
    int n = idx >> 7, k = idx & 127;
    WKVT[idx] = f2b((n < 128) ? Wk[k * 128 + n] : Wv[k * 128 + (n - 128)]);
    return;
  }
  idx -= 32768;
  if (idx < 256) { BKV[idx] = (idx < 128) ? bk[idx] : bv[idx - 128]; return; }
  idx -= 256;
  if (idx < 128) {
    float s = bq[idx];
    for (int u = 0; u < 128; u++) s += bq_in[u] * Wq[u * 128 + idx];
    BQQ[idx] = s;
    return;
  }
  idx -= 128;
  if (idx < 1024) {
    float s = bc[idx];
    for (int u = 0; u < 128; u++) s += bo[u] * Wc[u * 1024 + idx];
    BOC[idx] = s;
    return;
  }
  idx -= 1024;
  if (idx < 131072) { WQINB[idx] = f2b(Wq_in[idx]); return; }
  idx -= 131072;
  if (idx < 16384) { WOB[idx] = f2b(Wo[idx]); return; }
}

// ---------------------------------------------------------------------------
__global__ void attn_kernel(const bf16* __restrict__ qh, const bf16* __restrict__ kvh,
                            bf16* __restrict__ apre, float* __restrict__ attw)
{
  const int b = blockIdx.x, t = threadIdx.x;  // 128 threads
  float q = b2f(qh[(size_t)b * 128 + t]);
  const bf16* kv = kvh + (size_t)b * 3 * 256;
  float s[3], v[3];
#pragma unroll
  for (int i = 0; i < 3; i++) {
    float k = b2f(kv[i * 256 + t]);
    v[i] = b2f(kv[i * 256 + 128 + t]);
    float r = q * k;
#pragma unroll
    for (int off = 16; off > 0; off >>= 1) r += __shfl_down(r, off, 32);
    r = __shfl(r, 0, 32);
    s[i] = r * 0.17677669529663687f;  // 1/sqrt(32)
  }
  float mx = fmaxf(s[0], fmaxf(s[1], s[2]));
  float e0 = __expf(s[0] - mx), e1 = __expf(s[1] - mx), e2 = __expf(s[2] - mx);
  float inv = 1.f / (e0 + e1 + e2);
  float w0 = e0 * inv, w1 = e1 * inv, w2 = e2 * inv;
  apre[(size_t)b * 128 + t] = f2b(w0 * v[0] + w1 * v[1] + w2 * v[2]);
  __shared__ float aw[4][3];
  if ((t & 31) == 0) { int h = t >> 5; aw[h][0] = w0; aw[h][1] = w1; aw[h][2] = w2; }
  __syncthreads();
  if (t < 3)
    attw[(size_t)b * 3 + t] = 0.25f * (aw[0][t] + aw[1][t] + aw[2][t] + aw[3][t]);
}

// ---------------------------------------------------------------------------
__global__ void ln_out_kernel(const bf16* __restrict__ x, const float* __restrict__ g,
                              const float* __restrict__ bb, float* __restrict__ out)
{
  const int row = blockIdx.x, t = threadIdx.x;
  const bf16* xr = x + (size_t)row * 1024;
  ushort4 u = *reinterpret_cast<const ushort4*>(xr + t * 4);
  float v0 = __uint_as_float((uint32_t)u.x << 16);
  float v1 = __uint_as_float((uint32_t)u.y << 16);
  float v2 = __uint_as_float((uint32_t)u.z << 16);
  float v3 = __uint_as_float((uint32_t)u.w << 16);
  float s = v0 + v1 + v2 + v3;
  float s2 = v0 * v0 + v1 * v1 + v2 * v2 + v3 * v3;
#pragma unroll
  for (int off = 32; off > 0; off >>= 1) {
    s += __shfl_down(s, off, 64);
    s2 += __shfl_down(s2, off, 64);
  }
  __shared__ float ls[4], ls2[4];
  const int w = t >> 6;
  if ((t & 63) == 0) { ls[w] = s; ls2[w] = s2; }
  __syncthreads();
  float S = ls[0] + ls[1] + ls[2] + ls[3];
  float S2 = ls2[0] + ls2[1] + ls2[2] + ls2[3];
  float mean = S * (1.f / 1024.f);
  float var = S2 * (1.f / 1024.f) - mean * mean;
  float rstd = rsqrtf(var + 1e-5f);
  const int c = t * 4;
  float4 o;
  o.x = (v0 - mean) * rstd * g[c + 0] + bb[c + 0];
  o.y = (v1 - mean) * rstd * g[c + 1] + bb[c + 1];
  o.z = (v2 - mean) * rstd * g[c + 2] + bb[c + 2];
  o.w = (v3 - mean) * rstd * g[c + 3] + bb[c + 3];
  *reinterpret_cast<float4*>(out + (size_t)row * 1024 + c) = o;
}

// ---------------------------------------------------------------------------
extern "C" void kernel_launch(void* const* d_in, const int* in_sizes, int n_in,
                              void* d_out, int out_size, void* d_ws, size_t ws_size,
                              hipStream_t stream)
{
  const float* ff   = (const float*)d_in[0];
  const float* exl  = (const float*)d_in[1];
  const float* iml  = (const float*)d_in[2];
  const float* affv = (const float*)d_in[3];
  const float* geg = (const float*)d_in[4],  *geb = (const float*)d_in[5];
  const float* Wex = (const float*)d_in[6],  *bex = (const float*)d_in[7];
  const float* gig = (const float*)d_in[8],  *gib = (const float*)d_in[9];
  const float* Wim = (const float*)d_in[10], *bim = (const float*)d_in[11];
  const float* gag = (const float*)d_in[12], *gab = (const float*)d_in[13];
  const float* Waf = (const float*)d_in[14], *baf = (const float*)d_in[15];
  const float* Wq_in = (const float*)d_in[16], *bq_in = (const float*)d_in[17];
  const float* Wq = (const float*)d_in[18], *bq = (const float*)d_in[19];
  const float* Wk = (const float*)d_in[20], *bk = (const float*)d_in[21];
  const float* Wv = (const float*)d_in[22], *bv = (const float*)d_in[23];
  const float* Wo = (const float*)d_in[24], *bo = (const float*)d_in[25];
  const float* Wc = (const float*)d_in[26], *bc = (const float*)d_in[27];
  const float* Ws = (const float*)d_in[28], *bs = (const float*)d_in[29];
  const float* Wg1 = (const float*)d_in[30], *bg1 = (const float*)d_in[31];
  const float* Wg2 = (const float*)d_in[32], *bg2 = (const float*)d_in[33];
  const float* lng = (const float*)d_in[34], *lnb = (const float*)d_in[35];

  // workspace layout (bytes); peak = 62,199,296 (~59.3 MB)
  char* ws = (char*)d_ws;
  bf16*  WKVT = (bf16*)(ws + 0);         //  32768 el bf16
  float* BKV  = (float*)(ws + 65536);    //    256 el f32
  bf16*  WQQT = (bf16*)(ws + 66560);     // 131072 el bf16
  float* BQQ  = (float*)(ws + 328704);   //    128 el f32
  bf16*  WOCT = (bf16*)(ws + 329216);    // 131072 el bf16
  float* BOC  = (float*)(ws + 591360);   //   1024 el f32
  bf16*  WST  = (bf16*)(ws + 595456);    // 393216 el bf16
  bf16*  WG1T = (bf16*)(ws + 1381888);   // 2097152 el bf16
  bf16*  WG2T = (bf16*)(ws + 5576192);   // 1048576 el bf16
  bf16*  FFB  = (bf16*)(ws + 7673344);   // B*1024 (live: preamble..big6)
  bf16*  PRE  = (bf16*)(ws + 7673344);   // B*1024, aliases FFB elem-wise (big6..ln)
  bf16*  TOK  = (bf16*)(ws + 41227776);  // B*384  (live: preamble..big6/G4)
  bf16*  QH   = (bf16*)(ws + 53810688);  // B*128  (live: g12..attn)
  bf16*  APRE = (bf16*)(ws + 58004992);  // B*128  (live: attn..big5)

  // prep temporaries carved from the (not-yet-live) QH slot (4 MB avail):
  bf16* WQT   = (bf16*)(ws + 53810688);            //  16384 el (Wq^T)
  bf16* WOB   = (bf16*)(ws + 53810688 + 32768);    //  16384 el (Wo bf16)
  bf16* WQINB = (bf16*)(ws + 53810688 + 65536);    // 131072 el (Wq_in bf16)
  bf16* WCT   = (bf16*)(ws + 53810688 + 327680);   // 131072 el (Wc^T)

  float* outp = (float*)d_out;
  float* out_refined = outp;             // B*1024 f32 (64MB region)
  float* out_attw    = outp + 16777216;  // B*3 f32
  float* out_summary = outp + 16826368;  // B*1024 f32 (64MB region)
  // scratch hosted in out regions:
  bf16* CTX   = (bf16*)out_refined;                              // [0,32M) big5..big6
  bf16* GATEH = (bf16*)((char*)out_refined + 33554432);          // [32M,64M) big5..big6
  bf16* KVH   = (bf16*)out_summary;                              // [0,25.2M) g12..attn
  bf16* WOC   = (bf16*)((char*)out_summary + 33554432);          // 256KB folds_a..g12
  bf16* WFOLD = (bf16*)((char*)out_summary + 34603008);          // 256KB g12..big5
  float* BG1F = (float*)((char*)out_summary + 35127296);         // 4KB  folds_a..big5

  // 1: preamble — ffb + tokens + transposes + prep scatter
  preamble<<<20694, 256, 0, stream>>>(
      ff, FFB, exl, iml, affv, geg, geb, Wex, bex, gig, gib, Wim, bim,
      gag, gab, Waf, baf, TOK,
      Wq, Wc, Ws, Wg1, Wg2, WQT, WCT, WST, WG1T, WG2T,
      Wk, bk, Wv, bv, Wq_in, bq_in, bq, Wo, bo, bc,
      WKVT, BKV, BQQ, BOC, WQINB, WOB);
  // 2: folds A (WQQT, WOCT, WOC, BG1F)
  folds_a<<<28, 256, 0, stream>>>(WQT, WQINB, WQQT, WCT, WOB, WOCT, WOC,
                                  Wg1, BOC, bg1, BG1F);
  // 3: G2 + G1 + WFOLD
  g12_k<<<904, 256, 0, stream>>>(FFB, WQQT, BQQ, QH, TOK, WKVT, BKV, KVH,
                                 WG1T, WOC, WFOLD);
  // 4: attention
  attn_kernel<<<16384, 128, 0, stream>>>(QH, KVH, APRE, out_attw);
  // 5: G5 (folded, K=1152) || G3 (K=128)
  big5_k<<<512, 512, 0, stream>>>(FFB, APRE, WG1T, WFOLD, BG1F, GATEH,
                                  WOCT, BOC, CTX);
  // 6: G6 || G4
  big6_k<<<512, 512, 0, stream>>>(GATEH, WG2T, bg2, PRE, FFB, CTX,
                                  TOK, WST, bs, out_summary);
  // 7: final LN
  ln_out_kernel<<<16384, 256, 0, stream>>>(PRE, lng, lnb, out_refined);
}